// Round 10
// baseline (194.879 us; speedup 1.0000x reference)
//
#include <hip/hip_runtime.h>

// ADI diffusion B=16, C=8, S=128, 10 steps. Round 10: occupancy doubling.
// Same register-run Jacobi-2 structure as round 9, but 512 blocks x 256
// threads (4-row strips, 8-row halo tile) and a single in-place LDS region
// (~50 KB/block) -> 2 blocks/CU = 16 waves/CU (was 8). X2 recomputes rb/g
// from the staged co so no persistent coeff VGPRs; LB(256,4) caps VGPR<=128.
// Launch gap measured ~0 (graph replay), so per-kernel latency is the target.

constexpr int S_ = 128;
constexpr int RS = 129;             // padded LDS row stride (w-run reads)
constexpr float EPSF = 1e-6f;
constexpr float DT2 = 0.0005f;

// LDS float offsets: A = data tile (head: 64 rows c*8+hh; main: 32 rows c*4+i)
//                    C = x-coeff co, 32 rows (owned)
constexpr int OFF_A = 0;
constexpr int OFF_C = 64 * RS;           // 8256
constexpr int POOLF = OFF_C + 32 * RS;   // 12384 floats = 49.5 KB

__device__ __forceinline__ void jrun12(const float (&e)[12], const float (&g)[12],
                                       float (&o)[8]) {
    float x1[12];
    #pragma unroll
    for (int i = 1; i <= 10; ++i) x1[i] = fmaf(g[i], e[i - 1] + e[i + 1], e[i]);
    #pragma unroll
    for (int i = 2; i <= 9; ++i) o[i - 2] = fmaf(g[i], x1[i - 1] + x1[i + 1], e[i]);
}

__device__ __forceinline__ void jrun8(const float (&e)[8], const float (&g)[8],
                                      float (&o)[4]) {
    float x1[8];
    #pragma unroll
    for (int i = 1; i <= 6; ++i) x1[i] = fmaf(g[i], e[i - 1] + e[i + 1], e[i]);
    #pragma unroll
    for (int i = 2; i <= 5; ++i) o[i - 2] = fmaf(g[i], x1[i - 1] + x1[i + 1], e[i]);
}

template <bool HEAD, bool TAILMIX>
__global__ __launch_bounds__(256, 4) void step_kernel(
    const float* __restrict__ usrc, float* __restrict__ udst,
    const float* __restrict__ ab, const float* __restrict__ atc,
    const float* __restrict__ bbeta, const float* __restrict__ btc,
    const float* __restrict__ cm, float t_y, float t_x)
{
    __shared__ float sP[POOLF];
    const int tid = threadIdx.x;
    const int b   = blockIdx.x >> 5;
    const int h0  = (blockIdx.x & 31) << 2;     // owned rows h0..h0+3

    float M[64];                                 // uniform -> SGPRs
    #pragma unroll
    for (int i = 0; i < 64; ++i) M[i] = cm[i];

    if (HEAD) {
        // stage 8-row tile (rows c*8+hh), lanes sweep w (coalesced)
        #pragma unroll
        for (int m = 0; m < 4; ++m) {
            const int col = tid + 256 * m;
            const int c = col >> 7, w = col & 127;
            #pragma unroll
            for (int hh = 0; hh < 8; ++hh) {
                const int gh = h0 - 2 + hh;
                float v = 0.f;
                if (gh >= 0 && gh < S_) v = usrc[((b * 8 + c) * S_ + gh) * S_ + w];
                sP[OFF_A + (c * 8 + hh) * RS + w] = v;
            }
        }
        __syncthreads();
        // mix in place (thread owns its (hh,w) point across all c)
        #pragma unroll
        for (int m = 0; m < 4; ++m) {
            const int p = tid + 256 * m;
            const int hh = p >> 7, w = p & 127;
            float v[8], o[8];
            #pragma unroll
            for (int c = 0; c < 8; ++c) v[c] = sP[OFF_A + (c * 8 + hh) * RS + w];
            #pragma unroll
            for (int dd = 0; dd < 8; ++dd) {
                float a = 0.f;
                #pragma unroll
                for (int c = 0; c < 8; ++c) a = fmaf(M[dd * 8 + c], v[c], a);
                o[dd] = a;
            }
            #pragma unroll
            for (int c = 0; c < 8; ++c) sP[OFF_A + (c * 8 + hh) * RS + w] = o[c];
        }
        __syncthreads();
        // x@0 on all 64 tile rows, 16 w-runs each; in-place via reg stash
        float xo[4][8];
        #pragma unroll
        for (int m = 0; m < 4; ++m) {
            const int run = tid + 256 * m;
            const int r = run & 63, w0 = (run >> 6) * 8;
            const int c = r >> 3, hh = r & 7;
            const int gh = h0 - 2 + hh;
            const bool rowin = (gh >= 0 && gh < S_);
            const int ghc = min(max(gh, 0), S_ - 1);
            float e[12], g[12];
            #pragma unroll
            for (int j = 0; j < 12; ++j) {
                const int wj = w0 - 2 + j;
                const bool win = (wj >= 0 && wj < S_);
                const int wjc = min(max(wj, 0), S_ - 1);
                float al = ab[(c * S_ + ghc) * S_ + wjc];
                al = fminf(fmaxf(al, EPSF), 10.f);
                const float co = (rowin && win) ? al * 0.0005f : 0.f;
                const float dv = win ? sP[OFF_A + r * RS + wjc] : 0.f;
                const float nb = (wj == 0 || wj == S_ - 1) ? 1.f : 2.f;
                const float rb = __builtin_amdgcn_rcpf(fmaf(nb, co, 1.f) + EPSF);
                e[j] = rb * dv; g[j] = rb * co;
            }
            jrun12(e, g, xo[m]);
        }
        __syncthreads();
        #pragma unroll
        for (int m = 0; m < 4; ++m) {
            const int run = tid + 256 * m;
            const int r = run & 63, w0 = (run >> 6) * 8;
            #pragma unroll
            for (int i = 0; i < 8; ++i) sP[OFF_A + r * RS + w0 + i] = xo[m][i];
        }
        __syncthreads();
    }

    // ---- Y: 1024 (c,w) cols, 4/thread; 8-row register solve -> 4 owned rows
    float oy[4][4];
    #pragma unroll
    for (int m = 0; m < 4; ++m) {
        const int col = tid + 256 * m;
        const int c = col >> 7, w = col & 127;
        float e[8], g[8];
        #pragma unroll
        for (int hh = 0; hh < 8; ++hh) {
            const int gh = h0 - 2 + hh;
            const bool inr = (gh >= 0 && gh < S_);
            const int ghc = min(max(gh, 0), S_ - 1);
            float dv;
            if (HEAD) dv = sP[OFF_A + (c * 8 + hh) * RS + w];
            else {
                dv = usrc[((b * 8 + c) * S_ + ghc) * S_ + w];
                dv = inr ? dv : 0.f;
            }
            const int gc = (c * S_ + ghc) * S_ + w;
            float be = fmaf(btc[gc], t_y, bbeta[gc]);
            be = fminf(fmaxf(be, EPSF), 10.f);
            const float co = inr ? be * 0.001f : 0.f;
            const float nb = (gh == 0 || gh == S_ - 1) ? 1.f : 2.f;
            const float rb = __builtin_amdgcn_rcpf(fmaf(nb, co, 1.f) + EPSF);
            e[hh] = rb * dv; g[hh] = rb * co;
        }
        jrun8(e, g, oy[m]);
    }
    if (HEAD) __syncthreads();     // A reads done before overwrite
    #pragma unroll
    for (int m = 0; m < 4; ++m) {
        const int col = tid + 256 * m;
        const int c = col >> 7, w = col & 127;
        #pragma unroll
        for (int i = 0; i < 4; ++i) sP[OFF_A + (c * 4 + i) * RS + w] = oy[m][i];
    }
    // x-coeff co for owned 32 rows (coalesced), region C
    #pragma unroll
    for (int m = 0; m < 16; ++m) {
        const int p = tid + 256 * m;
        const int r = p >> 7, w = p & 127;         // r = c*4 + ho
        const int c = r >> 2, ho = r & 3;
        const int gc = (c * S_ + h0 + ho) * S_ + w;
        float al = fmaf(atc[gc], t_x, ab[gc]);
        al = fminf(fmaxf(al, EPSF), 10.f);
        sP[OFF_C + r * RS + w] = al * 0.0005f;
    }
    __syncthreads();

    // ---- X1: 32 rows x 16 runs, 2/thread
    float xo[2][8];
    #pragma unroll
    for (int m = 0; m < 2; ++m) {
        const int run = tid + 256 * m;
        const int r = run & 31, w0 = (run >> 5) * 8;
        float e[12], g[12];
        #pragma unroll
        for (int j = 0; j < 12; ++j) {
            const int wj = w0 - 2 + j;
            const bool win = (wj >= 0 && wj < S_);
            const int wjc = min(max(wj, 0), S_ - 1);
            const float co = win ? sP[OFF_C + r * RS + wjc] : 0.f;
            const float dv = win ? sP[OFF_A + r * RS + wjc] : 0.f;
            const float nb = (wj == 0 || wj == S_ - 1) ? 1.f : 2.f;
            const float rb = __builtin_amdgcn_rcpf(fmaf(nb, co, 1.f) + EPSF);
            e[j] = rb * dv; g[j] = rb * co;
        }
        jrun12(e, g, xo[m]);
    }

    if (TAILMIX) {
        __syncthreads();
        #pragma unroll
        for (int m = 0; m < 2; ++m) {
            const int run = tid + 256 * m;
            const int r = run & 31, w0 = (run >> 5) * 8;
            #pragma unroll
            for (int i = 0; i < 8; ++i) sP[OFF_A + r * RS + w0 + i] = xo[m][i];
        }
        __syncthreads();
        // mix in place: 512 points, 2/thread
        #pragma unroll
        for (int m = 0; m < 2; ++m) {
            const int p = tid + 256 * m;
            const int ho = p >> 7, w = p & 127;
            float v[8], o[8];
            #pragma unroll
            for (int c = 0; c < 8; ++c) v[c] = sP[OFF_A + (c * 4 + ho) * RS + w];
            #pragma unroll
            for (int dd = 0; dd < 8; ++dd) {
                float a = 0.f;
                #pragma unroll
                for (int c = 0; c < 8; ++c) a = fmaf(M[dd * 8 + c], v[c], a);
                o[dd] = a;
            }
            #pragma unroll
            for (int c = 0; c < 8; ++c) sP[OFF_A + (c * 4 + ho) * RS + w] = o[c];
        }
        __syncthreads();
        // X2: same runs/t; recompute rb,g from C (no persistent coeff regs)
        #pragma unroll
        for (int m = 0; m < 2; ++m) {
            const int run = tid + 256 * m;
            const int r = run & 31, w0 = (run >> 5) * 8;
            const int c = r >> 2, ho = r & 3;
            float e[12], g[12];
            #pragma unroll
            for (int j = 0; j < 12; ++j) {
                const int wj = w0 - 2 + j;
                const bool win = (wj >= 0 && wj < S_);
                const int wjc = min(max(wj, 0), S_ - 1);
                const float co = win ? sP[OFF_C + r * RS + wjc] : 0.f;
                const float dv = win ? sP[OFF_A + r * RS + wjc] : 0.f;
                const float nb = (wj == 0 || wj == S_ - 1) ? 1.f : 2.f;
                const float rb = __builtin_amdgcn_rcpf(fmaf(nb, co, 1.f) + EPSF);
                e[j] = rb * dv; g[j] = rb * co;
            }
            float o[8]; jrun12(e, g, o);
            float4* dst4 = (float4*)&udst[((b * 8 + c) * S_ + h0 + ho) * S_ + w0];
            dst4[0] = make_float4(o[0], o[1], o[2], o[3]);
            dst4[1] = make_float4(o[4], o[5], o[6], o[7]);
        }
    } else {
        #pragma unroll
        for (int m = 0; m < 2; ++m) {
            const int run = tid + 256 * m;
            const int r = run & 31, w0 = (run >> 5) * 8;
            const int c = r >> 2, ho = r & 3;
            float4* dst4 = (float4*)&udst[((b * 8 + c) * S_ + h0 + ho) * S_ + w0];
            dst4[0] = make_float4(xo[m][0], xo[m][1], xo[m][2], xo[m][3]);
            dst4[1] = make_float4(xo[m][4], xo[m][5], xo[m][6], xo[m][7]);
        }
    }
}

extern "C" void kernel_launch(void* const* d_in, const int* in_sizes, int n_in,
                              void* d_out, int out_size, void* d_ws, size_t ws_size,
                              hipStream_t stream) {
    const float* u_in = (const float*)d_in[0];
    const float* ab   = (const float*)d_in[1];
    const float* bbta = (const float*)d_in[2];
    const float* atc  = (const float*)d_in[3];
    const float* btc  = (const float*)d_in[4];
    const float* cm   = (const float*)d_in[5];
    float* uo = (float*)d_out;
    float* uw = (float*)d_ws;     // 8 MB ping buffer

    const dim3 g(512), blk(256);

    // k=0: head(mix|x@0) + y@0.5 + x@1|mix|x@1, pristine input -> ws
    step_kernel<true, true><<<g, blk, 0, stream>>>(u_in, uw, ab, atc, bbta, btc, cm,
                                                   1 * DT2, 2 * DT2);
    const float* src = uw; float* dst = uo;
    for (int k = 1; k <= 8; ++k) {
        step_kernel<false, true><<<g, blk, 0, stream>>>(src, dst, ab, atc, bbta, btc, cm,
                                                        (2 * k + 1) * DT2, (2 * k + 2) * DT2);
        const float* ns = dst; dst = (dst == uo) ? uw : uo; src = ns;
    }
    // k=9: y@9.5 + x@10 (no mix) -> d_out (parity: src=uw, dst=uo)
    step_kernel<false, false><<<g, blk, 0, stream>>>(src, dst, ab, atc, bbta, btc, cm,
                                                     19 * DT2, 20 * DT2);
}

// Round 11
// 191.200 us; speedup vs baseline: 1.0192x; 1.0192x over previous
//
#include <hip/hip_runtime.h>

// ADI diffusion B=16, C=8, S=128, 10 steps. Round 11: R9 geometry (10
// kernels, 256 blocks x 512 threads, 8-row strips, 12-row y-tile) but all
// global reads are float4 coalesced STAGING passes into LDS, and every
// compute stage (y-solve, x-solves, mix) reads LDS only. Masks folded into
// staging. Jacobi-2 in registers (jrun12). Ping-pong d_out <-> d_ws.

constexpr int S_ = 128;
constexpr int RS = 129;                  // padded LDS row stride
constexpr float EPSF = 1e-6f;
constexpr float DT2 = 0.0005f;
constexpr int OFF_C = 96 * RS;           // A: 96 rows, C: 96 rows
constexpr int POOLF = 2 * 96 * RS;       // 24768 floats = 99 KB

__device__ __forceinline__ void jrun12(const float (&e)[12], const float (&g)[12],
                                       float (&o)[8]) {
    float x1[12];
    #pragma unroll
    for (int i = 1; i <= 10; ++i) x1[i] = fmaf(g[i], e[i - 1] + e[i + 1], e[i]);
    #pragma unroll
    for (int i = 2; i <= 9; ++i) o[i - 2] = fmaf(g[i], x1[i - 1] + x1[i + 1], e[i]);
}

__device__ __forceinline__ float clip1(float a) {
    return fminf(fmaxf(a, EPSF), 10.f);
}

template <bool HEAD, bool TAILMIX>
__global__ __launch_bounds__(512, 2) void step_kernel(
    const float* __restrict__ usrc, float* __restrict__ udst,
    const float* __restrict__ ab, const float* __restrict__ atc,
    const float* __restrict__ bbeta, const float* __restrict__ btc,
    const float* __restrict__ cm, float t_y, float t_x)
{
    __shared__ float sP[POOLF];
    float* __restrict__ sA = sP;             // data rows
    float* __restrict__ sC = sP + OFF_C;     // coeff rows
    const int tid = threadIdx.x;
    const int b  = blockIdx.x >> 4;
    const int h0 = (blockIdx.x & 15) << 3;   // owned rows h0..h0+7

    float M[64];                             // uniform -> scalar regs
    if (HEAD || TAILMIX) {
        #pragma unroll
        for (int i = 0; i < 64; ++i) M[i] = cm[i];
    }

    // ---- staging pass 1: A <- u tile (96 rows r=c*12+hh), C <- HEAD?alpha0:beta(t_y)
    #pragma unroll
    for (int m = 0; m < 6; ++m) {
        const int idx = tid + 512 * m;               // 3072 quads
        const int r = idx >> 5, wq = (idx & 31) << 2;
        const int c = r / 12, hh = r - 12 * c;
        const int gh = h0 - 2 + hh;
        const bool inr = (gh >= 0 && gh < S_);
        const int ghc = inr ? gh : 0;
        const int gb = (c * S_ + ghc) * S_ + wq;
        float4 uv = make_float4(0.f, 0.f, 0.f, 0.f);
        float4 cv = make_float4(0.f, 0.f, 0.f, 0.f);
        if (inr) {
            uv = *(const float4*)&usrc[((b * 8 + c) * S_ + ghc) * S_ + wq];
            if (HEAD) {
                const float4 a4 = *(const float4*)&ab[gb];
                cv.x = clip1(a4.x) * 0.0005f; cv.y = clip1(a4.y) * 0.0005f;
                cv.z = clip1(a4.z) * 0.0005f; cv.w = clip1(a4.w) * 0.0005f;
            } else {
                const float4 b4 = *(const float4*)&bbeta[gb];
                const float4 t4 = *(const float4*)&btc[gb];
                cv.x = clip1(fmaf(t4.x, t_y, b4.x)) * 0.001f;
                cv.y = clip1(fmaf(t4.y, t_y, b4.y)) * 0.001f;
                cv.z = clip1(fmaf(t4.z, t_y, b4.z)) * 0.001f;
                cv.w = clip1(fmaf(t4.w, t_y, b4.w)) * 0.001f;
            }
        }
        *(float4*)&sA[r * RS + wq] = uv;
        *(float4*)&sC[r * RS + wq] = cv;
    }
    __syncthreads();

    if (HEAD) {
        // mix on 1536 points (hh,w), in-place (each point thread-exclusive)
        #pragma unroll
        for (int m = 0; m < 3; ++m) {
            const int p = tid + 512 * m;
            const int hh = p >> 7, w = p & 127;
            float v[8], o[8];
            #pragma unroll
            for (int c = 0; c < 8; ++c) v[c] = sA[(c * 12 + hh) * RS + w];
            #pragma unroll
            for (int dd = 0; dd < 8; ++dd) {
                float a = 0.f;
                #pragma unroll
                for (int c = 0; c < 8; ++c) a = fmaf(M[dd * 8 + c], v[c], a);
                o[dd] = a;
            }
            #pragma unroll
            for (int c = 0; c < 8; ++c) sA[(c * 12 + hh) * RS + w] = o[c];
        }
        __syncthreads();
        // x@0 on 96 rows x 16 runs
        float x0[3][8];
        #pragma unroll
        for (int m = 0; m < 3; ++m) {
            const int idx = tid + 512 * m;
            const int r = idx % 96, w0 = (idx / 96) << 3;
            float e[12], g[12];
            #pragma unroll
            for (int j = 0; j < 12; ++j) {
                const int wj = w0 - 2 + j;
                const bool win = (wj >= 0 && wj < S_);
                const int wjc = min(max(wj, 0), S_ - 1);
                const float co = win ? sC[r * RS + wjc] : 0.f;
                const float dv = win ? sA[r * RS + wjc] : 0.f;
                const float nb = (wj == 0 || wj == S_ - 1) ? 1.f : 2.f;
                const float rb = __builtin_amdgcn_rcpf(fmaf(nb, co, 1.f) + EPSF);
                e[j] = rb * dv; g[j] = rb * co;
            }
            jrun12(e, g, x0[m]);
        }
        __syncthreads();
        #pragma unroll
        for (int m = 0; m < 3; ++m) {
            const int idx = tid + 512 * m;
            const int r = idx % 96, w0 = (idx / 96) << 3;
            #pragma unroll
            for (int i = 0; i < 8; ++i) sA[r * RS + w0 + i] = x0[m][i];
        }
        // stage C <- beta(t_y) (C_x0 readers finished at the barrier above)
        #pragma unroll
        for (int m = 0; m < 6; ++m) {
            const int idx = tid + 512 * m;
            const int r = idx >> 5, wq = (idx & 31) << 2;
            const int c = r / 12, hh = r - 12 * c;
            const int gh = h0 - 2 + hh;
            const bool inr = (gh >= 0 && gh < S_);
            float4 cv = make_float4(0.f, 0.f, 0.f, 0.f);
            if (inr) {
                const int gb = (c * S_ + gh) * S_ + wq;
                const float4 b4 = *(const float4*)&bbeta[gb];
                const float4 t4 = *(const float4*)&btc[gb];
                cv.x = clip1(fmaf(t4.x, t_y, b4.x)) * 0.001f;
                cv.y = clip1(fmaf(t4.y, t_y, b4.y)) * 0.001f;
                cv.z = clip1(fmaf(t4.z, t_y, b4.z)) * 0.001f;
                cv.w = clip1(fmaf(t4.w, t_y, b4.w)) * 0.001f;
            }
            *(float4*)&sC[r * RS + wq] = cv;
        }
        __syncthreads();
    }

    // ---- Y: 1024 (c,w) columns, 2/thread; LDS-only reads
    float oy[2][8];
    #pragma unroll
    for (int q = 0; q < 2; ++q) {
        const int col = tid + 512 * q;
        const int c = col >> 7, w = col & 127;
        float e[12], g[12];
        #pragma unroll
        for (int hh = 0; hh < 12; ++hh) {
            const int gh = h0 - 2 + hh;
            const float dv = sA[(c * 12 + hh) * RS + w];   // 0 outside domain
            const float co = sC[(c * 12 + hh) * RS + w];   // 0 outside domain
            const float nb = (gh == 0 || gh == S_ - 1) ? 1.f : 2.f;
            const float rb = __builtin_amdgcn_rcpf(fmaf(nb, co, 1.f) + EPSF);
            e[hh] = rb * dv; g[hh] = rb * co;
        }
        jrun12(e, g, oy[q]);
    }
    __syncthreads();
    // write owned 64 rows (r=c*8+ho) into A; stage C <- alpha(t_x), 64 rows
    #pragma unroll
    for (int q = 0; q < 2; ++q) {
        const int col = tid + 512 * q;
        const int c = col >> 7, w = col & 127;
        #pragma unroll
        for (int i = 0; i < 8; ++i) sA[(c * 8 + i) * RS + w] = oy[q][i];
    }
    #pragma unroll
    for (int m = 0; m < 4; ++m) {
        const int idx = tid + 512 * m;               // 2048 quads = 64 rows x 32
        const int r = idx >> 5, wq = (idx & 31) << 2;
        const int c = r >> 3, ho = r & 7;
        const int gb = (c * S_ + h0 + ho) * S_ + wq;
        const float4 a4 = *(const float4*)&ab[gb];
        const float4 t4 = *(const float4*)&atc[gb];
        float4 cv;
        cv.x = clip1(fmaf(t4.x, t_x, a4.x)) * 0.0005f;
        cv.y = clip1(fmaf(t4.y, t_x, a4.y)) * 0.0005f;
        cv.z = clip1(fmaf(t4.z, t_x, a4.z)) * 0.0005f;
        cv.w = clip1(fmaf(t4.w, t_x, a4.w)) * 0.0005f;
        *(float4*)&sC[r * RS + wq] = cv;
    }
    __syncthreads();

    // ---- X1: 64 rows x 16 runs, 2/thread
    float xo[2][8];
    #pragma unroll
    for (int m = 0; m < 2; ++m) {
        const int idx = tid + 512 * m;
        const int r = idx & 63, w0 = (idx >> 6) << 3;
        float e[12], g[12];
        #pragma unroll
        for (int j = 0; j < 12; ++j) {
            const int wj = w0 - 2 + j;
            const bool win = (wj >= 0 && wj < S_);
            const int wjc = min(max(wj, 0), S_ - 1);
            const float co = win ? sC[r * RS + wjc] : 0.f;
            const float dv = win ? sA[r * RS + wjc] : 0.f;
            const float nb = (wj == 0 || wj == S_ - 1) ? 1.f : 2.f;
            const float rb = __builtin_amdgcn_rcpf(fmaf(nb, co, 1.f) + EPSF);
            e[j] = rb * dv; g[j] = rb * co;
        }
        jrun12(e, g, xo[m]);
    }

    if (TAILMIX) {
        __syncthreads();
        #pragma unroll
        for (int m = 0; m < 2; ++m) {
            const int idx = tid + 512 * m;
            const int r = idx & 63, w0 = (idx >> 6) << 3;
            #pragma unroll
            for (int i = 0; i < 8; ++i) sA[r * RS + w0 + i] = xo[m][i];
        }
        __syncthreads();
        // mix on 1024 points (ho,w), in-place
        #pragma unroll
        for (int m = 0; m < 2; ++m) {
            const int p = tid + 512 * m;
            const int ho = p >> 7, w = p & 127;
            float v[8], o[8];
            #pragma unroll
            for (int c = 0; c < 8; ++c) v[c] = sA[(c * 8 + ho) * RS + w];
            #pragma unroll
            for (int dd = 0; dd < 8; ++dd) {
                float a = 0.f;
                #pragma unroll
                for (int c = 0; c < 8; ++c) a = fmaf(M[dd * 8 + c], v[c], a);
                o[dd] = a;
            }
            #pragma unroll
            for (int c = 0; c < 8; ++c) sA[(c * 8 + ho) * RS + w] = o[c];
        }
        __syncthreads();
        // X2: same runs, same coeffs; store direct
        #pragma unroll
        for (int m = 0; m < 2; ++m) {
            const int idx = tid + 512 * m;
            const int r = idx & 63, w0 = (idx >> 6) << 3;
            const int c = r >> 3, ho = r & 7;
            float e[12], g[12];
            #pragma unroll
            for (int j = 0; j < 12; ++j) {
                const int wj = w0 - 2 + j;
                const bool win = (wj >= 0 && wj < S_);
                const int wjc = min(max(wj, 0), S_ - 1);
                const float co = win ? sC[r * RS + wjc] : 0.f;
                const float dv = win ? sA[r * RS + wjc] : 0.f;
                const float nb = (wj == 0 || wj == S_ - 1) ? 1.f : 2.f;
                const float rb = __builtin_amdgcn_rcpf(fmaf(nb, co, 1.f) + EPSF);
                e[j] = rb * dv; g[j] = rb * co;
            }
            float o[8]; jrun12(e, g, o);
            float4* dst4 = (float4*)&udst[((b * 8 + c) * S_ + h0 + ho) * S_ + w0];
            dst4[0] = make_float4(o[0], o[1], o[2], o[3]);
            dst4[1] = make_float4(o[4], o[5], o[6], o[7]);
        }
    } else {
        #pragma unroll
        for (int m = 0; m < 2; ++m) {
            const int idx = tid + 512 * m;
            const int r = idx & 63, w0 = (idx >> 6) << 3;
            const int c = r >> 3, ho = r & 7;
            float4* dst4 = (float4*)&udst[((b * 8 + c) * S_ + h0 + ho) * S_ + w0];
            dst4[0] = make_float4(xo[m][0], xo[m][1], xo[m][2], xo[m][3]);
            dst4[1] = make_float4(xo[m][4], xo[m][5], xo[m][6], xo[m][7]);
        }
    }
}

extern "C" void kernel_launch(void* const* d_in, const int* in_sizes, int n_in,
                              void* d_out, int out_size, void* d_ws, size_t ws_size,
                              hipStream_t stream) {
    const float* u_in = (const float*)d_in[0];
    const float* ab   = (const float*)d_in[1];
    const float* bbta = (const float*)d_in[2];
    const float* atc  = (const float*)d_in[3];
    const float* btc  = (const float*)d_in[4];
    const float* cm   = (const float*)d_in[5];
    float* uo = (float*)d_out;
    float* uw = (float*)d_ws;     // 8 MB ping buffer

    const dim3 g(256), blk(512);

    // k=0: head(mix|x@0) + y@0.5 + x@1|mix|x@1, pristine input -> ws
    step_kernel<true, true><<<g, blk, 0, stream>>>(u_in, uw, ab, atc, bbta, btc, cm,
                                                   1 * DT2, 2 * DT2);
    const float* src = uw; float* dst = uo;
    for (int k = 1; k <= 8; ++k) {
        step_kernel<false, true><<<g, blk, 0, stream>>>(src, dst, ab, atc, bbta, btc, cm,
                                                        (2 * k + 1) * DT2, (2 * k + 2) * DT2);
        const float* ns = dst; dst = (dst == uo) ? uw : uo; src = ns;
    }
    // k=9: y@9.5 + x@10 (no mix) -> d_out (parity: src=uw, dst=uo)
    step_kernel<false, false><<<g, blk, 0, stream>>>(src, dst, ab, atc, bbta, btc, cm,
                                                     19 * DT2, 20 * DT2);
}